// Round 2
// baseline (274.800 us; speedup 1.0000x reference)
//
#include <hip/hip_runtime.h>
#include <cstdint>
#include <cstddef>

#define BB 128
#define NN 512
#define EE 512
#define KK 256
#define STR 17  // odd stride: column reads across 64 lanes hit all 32 banks (2-way = free)

__device__ __forceinline__ float wave_reduce_max(float v) {
#pragma unroll
  for (int off = 32; off >= 1; off >>= 1) v = fmaxf(v, __shfl_xor(v, off, 64));
  return v;
}
__device__ __forceinline__ float wave_reduce_sum(float v) {
#pragma unroll
  for (int off = 32; off >= 1; off >>= 1) v += __shfl_xor(v, off, 64);
  return v;
}

// Lower median (0-based rank 127) of 256 nonnegative values held 4 per lane
// across the 64 lanes of a wave. Exact: early-exit when exactly 128 values
// lie strictly below the pivot (their max is rank 127); otherwise bisection
// converges lo,hi to adjacent floats bracketing the answer (handles ties).
__device__ __forceinline__ float wave_median256(float a0, float a1, float a2, float a3) {
  float m = fmaxf(fmaxf(a0, a1), fmaxf(a2, a3));
  m = wave_reduce_max(m);
  float hi = __uint_as_float(__float_as_uint(m) + 1u);  // cnt(hi) == 256 >= 128
  float lo = 0.f;
  float pivot = hi;
  bool found = false;
  for (int it = 0; it < 40; ++it) {
    pivot = 0.5f * (lo + hi);
    int cnt = __popcll(__ballot(a0 < pivot)) + __popcll(__ballot(a1 < pivot)) +
              __popcll(__ballot(a2 < pivot)) + __popcll(__ballot(a3 < pivot));
    if (cnt == 128) { found = true; break; }
    if (cnt < 128) lo = pivot; else hi = pivot;
  }
  float p = found ? pivot : hi;
  float s0 = (a0 < p) ? a0 : 0.f;
  float s1 = (a1 < p) ? a1 : 0.f;
  float s2 = (a2 < p) ? a2 : 0.f;
  float s3 = (a3 < p) ? a3 : 0.f;
  return wave_reduce_max(fmaxf(fmaxf(s0, s1), fmaxf(s2, s3)));
}

// Fused: per block (b, g) covering 16 columns n0=g*16..+16 — stage the full
// 512x16 errs tile in LDS ONCE, compute both chunk-medians per column, the
// exp relaxation scalars, the per-block head-term partial sum, AND the
// partial dot exp_errs_part[e] = sum_{n in group} errs[b,e,n]*lam[b,n].
// errs is touched from HBM exactly once.
__global__ __launch_bounds__(256, 4) void kfused(
    const float* __restrict__ head, const float* __restrict__ errs,
    float* __restrict__ ws_delta, float* __restrict__ ws_htpart,
    float* __restrict__ ws_epart) {
  __shared__ float tile[512 * STR];  // 34816 B -> 4 blocks/CU
  __shared__ float medbuf[32];       // [chunk*16 + col]
  __shared__ float lambuf[16];
  __shared__ float redm[4];
  const int blk = blockIdx.x;
  const int b = blk >> 5, g = blk & 31;
  const int n0 = g * 16;
  const int tid = threadIdx.x, wave = tid >> 6, lane = tid & 63;

  // per-row head max (each block recomputes; 2 KB read, L2-hit for 31/32 blocks)
  float m = fmaxf(head[(size_t)b * NN + tid], head[(size_t)b * NN + 256 + tid]);
  m = wave_reduce_max(m);
  if (lane == 0) redm[wave] = m;

  // stage 512 rows x 16 cols
  const int tr = tid >> 2, tc = (tid & 3) * 4;
  const float* src = errs + (size_t)b * EE * NN + n0 + tc;
#pragma unroll
  for (int i = 0; i < 8; ++i) {
    int row = i * 64 + tr;
    float4 v = *(const float4*)(src + (size_t)row * NN);
    float* dst = &tile[row * STR + tc];
    dst[0] = v.x; dst[1] = v.y; dst[2] = v.z; dst[3] = v.w;
  }
  __syncthreads();
  float hmax = fmaxf(fmaxf(redm[0], redm[1]), fmaxf(redm[2], redm[3]));

  // 32 medians: pair p = chunk*16 + col, wave handles 8 pairs
#pragma unroll 1
  for (int jj = 0; jj < 8; ++jj) {
    int p = wave * 8 + jj;
    int col = p & 15;
    int rb = (p >> 4) * 256;
    float a0 = fabsf(tile[(rb + lane) * STR + col]);
    float a1 = fabsf(tile[(rb + lane + 64) * STR + col]);
    float a2 = fabsf(tile[(rb + lane + 128) * STR + col]);
    float a3 = fabsf(tile[(rb + lane + 192) * STR + col]);
    float med = wave_median256(a0, a1, a2, a3);
    if (lane == 0) medbuf[p] = med;
  }
  __syncthreads();

  // exp relaxation scalars for the 16 columns
  float htp = 0.f;
  if (tid < 16) {
    int n = n0 + tid;
    float l1 = medbuf[tid] + medbuf[16 + tid];
    float th = head[(size_t)b * NN + n] - hmax;
    float lb = th - l1, ub = th + l1;
    float lam, mu, delta;
    if (ub == lb) {
      lam = 0.f; mu = expf(ub); delta = 0.f;
    } else {
      float elb = expf(lb), eub = expf(ub);
      float lam_s = (eub - elb) / (ub - lb + 1e-6f);
      lam = fminf(lam_s, expf(lb + 0.9f));
      float ub0 = (lam > lam_s) ? (elb - lam * lb) : (eub - lam * ub);
      float t = lam * (1.f - logf(lam));
      mu = 0.5f * (t + ub0);
      delta = 0.5f * (ub0 - t);
    }
    lambuf[tid] = lam;
    ws_delta[(size_t)b * NN + n] = delta;
    htp = th * lam + mu;
  }
  if (wave == 0) {
    float s = wave_reduce_sum(htp);  // lanes 16..63 contribute 0
    if (lane == 0) ws_htpart[b * 32 + g] = s;
  }
  __syncthreads();

  // partial dots from the LDS tile (rows tid, tid+256)
  float s0 = 0.f, s1 = 0.f;
#pragma unroll
  for (int j = 0; j < 16; ++j) {
    float w = lambuf[j];
    s0 = fmaf(tile[tid * STR + j], w, s0);
    s1 = fmaf(tile[(tid + 256) * STR + j], w, s1);
  }
  float* op = ws_epart + ((size_t)(b * 32 + g)) * 512;
  op[tid] = s0;
  op[tid + 256] = s1;
}

// cexp part of exp_errs: full dot cauchy_exp[b,j,:] . delta[b,:], wave per row.
__global__ __launch_bounds__(256) void kcexp(
    const float* __restrict__ cexp, const float* __restrict__ ws_delta,
    float* __restrict__ ws_ee2) {
  const int blk = blockIdx.x;  // 512 blocks
  const int b = blk >> 2, part = blk & 3;
  const int wave = threadIdx.x >> 6, lane = threadIdx.x & 63;
  const float* wsrc = ws_delta + (size_t)b * NN;
  float4 wa = *(const float4*)(wsrc + 4 * lane);
  float4 wb = *(const float4*)(wsrc + 256 + 4 * lane);
  const int r0 = part * 64 + wave * 16;
  const float* base = cexp + (size_t)b * KK * NN;
  float* out = ws_ee2 + (size_t)b * KK;
#pragma unroll 1
  for (int i = 0; i < 16; ++i) {
    int r = r0 + i;
    const float* rp = base + (size_t)r * NN;
    float4 x = *(const float4*)(rp + 4 * lane);
    float4 y = *(const float4*)(rp + 256 + 4 * lane);
    float s = x.x * wa.x + x.y * wa.y + x.z * wa.z + x.w * wa.w +
              y.x * wb.x + y.y * wb.y + y.z * wb.z + y.w * wb.w;
    s = wave_reduce_sum(s);
    if (lane == 0) out[r] = s;
  }
}

// Stage 3: per b — combine 32 partials into exp_errs[0:512], append cexp dots,
// exp_head sum from htparts, 3 medians of 256, log relaxation, outputs.
__global__ __launch_bounds__(256) void kstage3(
    const float* __restrict__ head, const float* __restrict__ clog,
    const float* __restrict__ ws_htpart, const float* __restrict__ ws_epart,
    const float* __restrict__ ws_ee2, float* __restrict__ out) {
  __shared__ float eb[768];
  __shared__ float redm[4];
  __shared__ float meds[3];
  __shared__ float sc[2];
  __shared__ float ehsh;
  const int b = blockIdx.x;
  const int tid = threadIdx.x, wave = tid >> 6, lane = tid & 63;

  float m = fmaxf(head[(size_t)b * NN + tid], head[(size_t)b * NN + 256 + tid]);
  m = wave_reduce_max(m);
  if (lane == 0) redm[wave] = m;

  float acc0 = 0.f, acc1 = 0.f;
  const float* pp = ws_epart + (size_t)b * 32 * 512;
#pragma unroll
  for (int g = 0; g < 32; ++g) {
    acc0 += pp[g * 512 + tid];
    acc1 += pp[g * 512 + 256 + tid];
  }
  eb[tid] = acc0;
  eb[tid + 256] = acc1;
  eb[512 + tid >= 768 ? 0 : 512 + tid] = ws_ee2[(size_t)b * KK + tid];  // tid<256 always
  __syncthreads();

  if (wave < 3) {
    const float* p = eb + wave * 256;
    float a0 = fabsf(p[lane]), a1 = fabsf(p[lane + 64]);
    float a2 = fabsf(p[lane + 128]), a3 = fabsf(p[lane + 192]);
    float med = wave_median256(a0, a1, a2, a3);
    if (lane == 0) meds[wave] = med;
  } else {
    float v = (lane < 32) ? ws_htpart[b * 32 + lane] : 0.f;
    v = wave_reduce_sum(v);
    if (lane == 0) ehsh = v;
  }
  __syncthreads();

  if (tid == 0) {
    float hmax = fmaxf(fmaxf(redm[0], redm[1]), fmaxf(redm[2], redm[3]));
    float eh = ehsh;
    float l1 = meds[0] + meds[1] + meds[2];
    float lb = eh - l1, ub = eh + l1;
    float lam, mu, delta;
    if (ub == lb) {
      lam = 0.f; mu = logf(ub); delta = 0.f;
    } else {
      float llb = logf(lb + 1e-6f);
      float lam_s = (logf(ub) - llb) / (ub - lb + 1e-6f);
      lam = lam_s;
      float lb0 = llb - lb * lam;  // reference's where(lam<lam_s,...) always takes else
      float t = -logf(lam) - 1.f;
      mu = 0.5f * (t + lb0);
      delta = 0.5f * (t - lb0);
    }
    sc[0] = lam; sc[1] = delta;
    out[b] = eh * lam + mu + hmax;
  }
  __syncthreads();
  float lam = sc[0], delta = sc[1];
  float* ob = out + BB + (size_t)b * 1024;
  ob[tid] = eb[tid] * lam;
  ob[tid + 256] = eb[tid + 256] * lam;
  ob[tid + 512] = eb[tid + 512] * lam;
  ob[tid + 768] = delta * clog[(size_t)b * KK + tid];
}

extern "C" void kernel_launch(void* const* d_in, const int* in_sizes, int n_in,
                              void* d_out, int out_size, void* d_ws, size_t ws_size,
                              hipStream_t stream) {
  const float* head = (const float*)d_in[0];   // (128, 512)
  const float* errs = (const float*)d_in[1];   // (65536, 512)
  const float* cexp = (const float*)d_in[2];   // (128, 256, 512)
  const float* clog = (const float*)d_in[3];   // (128, 256)
  float* out = (float*)d_out;                  // 128 + 131072 floats

  float* ws = (float*)d_ws;
  float* ws_delta = ws;                        // 65536
  float* ws_htpart = ws_delta + BB * NN;       // 4096
  float* ws_ee2 = ws_htpart + BB * 32;         // 32768
  float* ws_epart = ws_ee2 + BB * KK;          // 128*32*512 = 2097152

  hipLaunchKernelGGL(kfused, dim3(BB * 32), dim3(256), 0, stream,
                     head, errs, ws_delta, ws_htpart, ws_epart);
  hipLaunchKernelGGL(kcexp, dim3(BB * 4), dim3(256), 0, stream,
                     cexp, ws_delta, ws_ee2);
  hipLaunchKernelGGL(kstage3, dim3(BB), dim3(256), 0, stream,
                     head, clog, ws_htpart, ws_epart, ws_ee2, out);
}